// Round 1
// baseline (75.885 us; speedup 1.0000x reference)
//
#include <hip/hip_runtime.h>

// TropConv2D: tropical conv = max_k(patch_k + w_kf) - min_k(patch_k + w_kf)
// x: (8, 32, 32, 32) f32 NHWC, w: (288, 64) f32, out: (8, 30, 30, 64) f32
// k ordering (TF extract_patches): k = (i*3 + j)*32 + c
//
// Layout: one block per output row (b, ho) -> grid = 8*30 = 240 blocks.
// 256 threads = 4 waves; lane = filter f (0..63); wave v handles pixels
// wo = v, v+4, v+8, ... (8 slots, predicated wo < 30).
// x rows [ho, ho+2] are contiguous in memory (12 KB) -> coalesced float4
// copy into LDS; patch reads are wave-uniform LDS broadcasts (conflict-free).
// Weight reads w[k*64 + lane] are lane-coalesced and L2-hot; held in regs
// per (i,j) chunk, amortized over the wave's 8 pixels.

#define C_IN 32
#define NF 64
#define H_OUT 30
#define W_OUT 30
#define W_IN 32

__global__ __launch_bounds__(256) void tropconv_kernel(
    const float* __restrict__ x,
    const float* __restrict__ w,
    float* __restrict__ out) {
    const int bho = blockIdx.x;           // 0..239  == b*30 + ho
    const int b = bho / H_OUT;
    const int ho = bho - b * H_OUT;
    const int tid = threadIdx.x;
    const int lane = tid & 63;            // filter index
    const int wave = tid >> 6;            // 0..3

    __shared__ float xs[3 * W_IN * C_IN]; // 3 rows x 32 cols x 32 ch = 12 KB

    // Cooperative staging: 3 contiguous input rows = 3072 floats = 768 float4
    const float4* __restrict__ xsrc =
        (const float4*)(x + (size_t)(b * 32 + ho) * (W_IN * C_IN));
    float4* xdst = (float4*)xs;
    #pragma unroll
    for (int r = 0; r < 3; ++r) {
        xdst[tid + r * 256] = xsrc[tid + r * 256];
    }
    __syncthreads();

    float mx[8], mn[8];
    #pragma unroll
    for (int t = 0; t < 8; ++t) { mx[t] = -INFINITY; mn[t] = INFINITY; }

    float wreg[C_IN];
    for (int ij = 0; ij < 9; ++ij) {      // (i,j) window position, i-major
        const int i = ij / 3;
        const int j = ij - i * 3;

        // weights for this (i,j) slice: w[(ij*32 + c)*64 + lane], c = 0..31
        const float* __restrict__ wp = w + (size_t)(ij * C_IN) * NF + lane;
        #pragma unroll
        for (int c = 0; c < C_IN; ++c) wreg[c] = wp[c * NF];

        const float* xrow = xs + i * (W_IN * C_IN) + j * C_IN;

        #pragma unroll
        for (int t = 0; t < 8; ++t) {
            const int wo = wave + 4 * t;
            if (wo < W_OUT) {             // wave-uniform predicate
                const float4* __restrict__ pp = (const float4*)(xrow + wo * C_IN);
                #pragma unroll
                for (int c4 = 0; c4 < C_IN / 4; ++c4) {
                    float4 p = pp[c4];    // broadcast ds_read_b128
                    float s0 = p.x + wreg[4 * c4 + 0];
                    float s1 = p.y + wreg[4 * c4 + 1];
                    float s2 = p.z + wreg[4 * c4 + 2];
                    float s3 = p.w + wreg[4 * c4 + 3];
                    // encourage v_max3 / v_min3 formation
                    mx[t] = fmaxf(fmaxf(mx[t], fmaxf(s0, s1)), fmaxf(s2, s3));
                    mn[t] = fminf(fminf(mn[t], fminf(s0, s1)), fminf(s2, s3));
                }
            }
        }
    }

    #pragma unroll
    for (int t = 0; t < 8; ++t) {
        const int wo = wave + 4 * t;
        if (wo < W_OUT) {
            out[((size_t)bho * W_OUT + wo) * NF + lane] = mx[t] - mn[t];
        }
    }
}

extern "C" void kernel_launch(void* const* d_in, const int* in_sizes, int n_in,
                              void* d_out, int out_size, void* d_ws, size_t ws_size,
                              hipStream_t stream) {
    const float* x = (const float*)d_in[0];   // 8*32*32*32 = 262144 floats
    const float* w = (const float*)d_in[1];   // 288*64 = 18432 floats
    float* out = (float*)d_out;               // 8*30*30*64 = 460800 floats

    dim3 grid(8 * H_OUT);                     // 240 blocks
    dim3 block(256);
    tropconv_kernel<<<grid, block, 0, stream>>>(x, w, out);
}

// Round 2
// 64.892 us; speedup vs baseline: 1.1694x; 1.1694x over previous
//
#include <hip/hip_runtime.h>

// TropConv2D: out[b,ho,wo,f] = max_k(patch_k + w[k,f]) - min_k(patch_k + w[k,f])
// x: (8,32,32,32) f32 NHWC, w: (288,64) f32, out: (8,30,30,64) f32
// k = (i*3 + j)*32 + c   (TF extract_patches ordering)
//
// v2: occupancy-driven restructure.
//   grid = 8*30*4 = 960 blocks (vs 240 in v1 -> was 1 wave/SIMD, latency-bound).
//   Each block: (b, ho, quarter q) -> pixels wo in [q*8, q*8+npx), npx = 8 (6 for q=3).
//   Block = 256 threads = 4 waves; lane = filter f; wave = channel-slice owner:
//   wave v covers c in [v*8, v*8+8) for ALL 9 (i,j) -> 72 k's per wave, so the
//   block reads each weight exactly once (72 KB/block, L1/L2-hot).
//   Max/min are associative -> k-split partials combined via LDS at the end
//   (bitwise-exact fp32).
//   Each wave keeps 8 pixel accumulators -> ILP 8 on the max/min chains.

#define C_IN 32
#define NF 64
#define H_OUT 30
#define W_OUT 30
#define W_IN 32

__global__ __launch_bounds__(256) void tropconv_kernel(
    const float* __restrict__ x,
    const float* __restrict__ w,
    float* __restrict__ out) {
    const int bx = blockIdx.x;            // 0..959
    const int q = bx & 3;                 // row quarter
    const int bho = bx >> 2;              // b*30 + ho
    const int b = bho / H_OUT;
    const int ho = bho - b * H_OUT;
    const int tid = threadIdx.x;
    const int lane = tid & 63;            // filter index
    const int wave = tid >> 6;            // channel-slice 0..3

    const int col0 = q * 8;
    const int npx = (q == 3) ? 6 : 8;     // block-uniform
    const int ncols = (q == 3) ? 8 : 10;  // input cols needed: col0 .. col0+npx+1

    // Patch tile: rows ho..ho+2, cols col0..col0+ncols-1, all 32 channels.
    __shared__ float xs[3 * 10 * C_IN];            // 3.75 KB (col stride 32)
    __shared__ float pmx[4][8][NF];                // 8 KB  partial max
    __shared__ float pmn[4][8][NF];                // 8 KB  partial min

    // ---- Stage patch rows (each row segment is contiguous in NHWC) ----
    {
        const int nf4_row = ncols * (C_IN / 4);    // 80 or 64 float4 per row
        const int total_f4 = 3 * nf4_row;          // 240 or 192 <= 256
        if (tid < total_f4) {
            const int r = tid / nf4_row;
            const int cc = tid - r * nf4_row;
            const float4* __restrict__ src = (const float4*)(
                x + ((size_t)((b * 32 + ho + r) * W_IN + col0)) * C_IN);
            ((float4*)xs)[r * 80 + cc] = src[cc];
        }
    }
    __syncthreads();

    float mx[8], mn[8];
    #pragma unroll
    for (int t = 0; t < 8; ++t) { mx[t] = -INFINITY; mn[t] = INFINITY; }

    for (int ij = 0; ij < 9; ++ij) {
        const int i = ij / 3;
        const int j = ij - i * 3;

        // weights for this wave's channel slice at window pos (i,j)
        float wreg[8];
        const float* __restrict__ wp =
            w + ((size_t)(ij * C_IN + wave * 8)) * NF + lane;
        #pragma unroll
        for (int cc = 0; cc < 8; ++cc) wreg[cc] = wp[cc * NF];

        #pragma unroll
        for (int px = 0; px < 8; ++px) {
            if (px < npx) {               // block-uniform predicate
                const float* __restrict__ pp =
                    xs + (i * 10 + (px + j)) * C_IN + wave * 8;
                float4 p0 = ((const float4*)pp)[0];   // broadcast ds_read_b128
                float4 p1 = ((const float4*)pp)[1];
                float s0 = p0.x + wreg[0];
                float s1 = p0.y + wreg[1];
                float s2 = p0.z + wreg[2];
                float s3 = p0.w + wreg[3];
                float s4 = p1.x + wreg[4];
                float s5 = p1.y + wreg[5];
                float s6 = p1.z + wreg[6];
                float s7 = p1.w + wreg[7];
                float hi = fmaxf(fmaxf(fmaxf(s0, s1), fmaxf(s2, s3)),
                                 fmaxf(fmaxf(s4, s5), fmaxf(s6, s7)));
                float lo = fminf(fminf(fminf(s0, s1), fminf(s2, s3)),
                                 fminf(fminf(s4, s5), fminf(s6, s7)));
                mx[px] = fmaxf(mx[px], hi);
                mn[px] = fminf(mn[px], lo);
            }
        }
    }

    // ---- Cross-wave combine (max/min associative -> exact) ----
    #pragma unroll
    for (int px = 0; px < 8; ++px) {
        pmx[wave][px][lane] = mx[px];
        pmn[wave][px][lane] = mn[px];
    }
    __syncthreads();

    const int nout = npx * NF;            // 512 or 384
    for (int e = tid; e < nout; e += 256) {
        const int px = e >> 6;
        const int f = e & 63;
        float a = fmaxf(fmaxf(pmx[0][px][f], pmx[1][px][f]),
                        fmaxf(pmx[2][px][f], pmx[3][px][f]));
        float m = fminf(fminf(pmn[0][px][f], pmn[1][px][f]),
                        fminf(pmn[2][px][f], pmn[3][px][f]));
        out[((size_t)bho * W_OUT + (col0 + px)) * NF + f] = a - m;
    }
}

extern "C" void kernel_launch(void* const* d_in, const int* in_sizes, int n_in,
                              void* d_out, int out_size, void* d_ws, size_t ws_size,
                              hipStream_t stream) {
    const float* x = (const float*)d_in[0];   // 8*32*32*32
    const float* w = (const float*)d_in[1];   // 288*64
    float* out = (float*)d_out;               // 8*30*30*64

    dim3 grid(8 * H_OUT * 4);                 // 960 blocks
    dim3 block(256);
    tropconv_kernel<<<grid, block, 0, stream>>>(x, w, out);
}